// Round 2
// baseline (1696.498 us; speedup 1.0000x reference)
//
#include <hip/hip_runtime.h>
#include <math.h>

#define B_ 512
#define T_ 128
#define VOCAB_ 50000

// ---------------------------------------------------------------------------
// proj kernel: out[row][0:2*U3] = concat(in_row @ Wf + bif, in_row @ Wb + bib)
// rows are (b,t) pairs, linear. If GATHER, in_row = emb[idx[row]].
// Block: TPB = 2*U3/3 threads; thread owns 3 cols {tid, tid+TPB, tid+2*TPB}.
// ROWS=8 rows per block; input tile staged transposed in LDS -> all inner
// reads are same-address broadcasts (conflict-free).
// ---------------------------------------------------------------------------
template<int K, int U3, bool GATHER>
__global__ void proj_kernel(const float* __restrict__ in,
                            const int* __restrict__ idx,
                            const float* __restrict__ emb,
                            const float* __restrict__ Wf, const float* __restrict__ Wb,
                            const float* __restrict__ bif, const float* __restrict__ bib,
                            float* __restrict__ out)
{
    constexpr int TPB  = 2 * U3 / 3;   // 128 (U3=192) or 64 (U3=96)
    constexpr int ROWS = 8;
    constexpr int NC   = 2 * U3;
    __shared__ float et[K * ROWS];     // [k][r]
    const int tid = threadIdx.x;
    const long row0 = (long)blockIdx.x * ROWS;

    constexpr int F4 = K / 4;          // float4 per row
    for (int i = tid; i < ROWS * F4; i += TPB) {
        int r = i / F4, q = i % F4;
        const float* src;
        if (GATHER) src = emb + (long)idx[row0 + r] * K + q * 4;
        else        src = in  + (row0 + r) * (long)K + q * 4;
        float4 v = *(const float4*)src;
        et[(q * 4 + 0) * ROWS + r] = v.x;
        et[(q * 4 + 1) * ROWS + r] = v.y;
        et[(q * 4 + 2) * ROWS + r] = v.z;
        et[(q * 4 + 3) * ROWS + r] = v.w;
    }
    __syncthreads();

    const float* wp[3];
    float acc[3][ROWS];
    #pragma unroll
    for (int g = 0; g < 3; g++) {
        int col = tid + g * TPB;
        const float* W  = (col < U3) ? Wf  : Wb;
        const float* bi = (col < U3) ? bif : bib;
        int cc = (col < U3) ? col : col - U3;
        wp[g] = W + cc;
        float b = bi[cc];
        #pragma unroll
        for (int r = 0; r < ROWS; r++) acc[g][r] = b;
    }

    for (int k = 0; k < K; k++) {
        float w0 = wp[0][(long)k * U3];
        float w1 = wp[1][(long)k * U3];
        float w2 = wp[2][(long)k * U3];
        const float4* e4 = (const float4*)&et[k * ROWS];
        float4 ea = e4[0], eb = e4[1];
        float ev[8] = {ea.x, ea.y, ea.z, ea.w, eb.x, eb.y, eb.z, eb.w};
        #pragma unroll
        for (int r = 0; r < ROWS; r++) {
            acc[0][r] = fmaf(ev[r], w0, acc[0][r]);
            acc[1][r] = fmaf(ev[r], w1, acc[1][r]);
            acc[2][r] = fmaf(ev[r], w2, acc[2][r]);
        }
    }

    #pragma unroll
    for (int g = 0; g < 3; g++) {
        int col = tid + g * TPB;
        for (int r = 0; r < ROWS; r++)
            out[(row0 + r) * NC + col] = acc[g][r];
    }
}

// ---------------------------------------------------------------------------
// GRU recurrence. One wave handles 64/U sequences; lane kp = lane % U owns
// state element h[kp] of its sequence. U matrix staged in LDS reordered as
// [j][kp][gate] (3 contiguous floats/lane, <=2 lanes/bank). Keras
// reset_after=True, gates z,r,h; activation relu.
// Grid: 2*NB blocks (first NB forward, next NB backward), SPB seqs/block.
// ---------------------------------------------------------------------------
template<int U, bool WRITE_ALL>
__global__ void gru_rec_kernel(const float* __restrict__ xz,   // [B*T][6U]
                               const float* __restrict__ Uwf, const float* __restrict__ Uwb,
                               const float* __restrict__ brf, const float* __restrict__ brb,
                               float* __restrict__ out, int NB)
{
    constexpr int U3  = 3 * U;
    constexpr int NC  = 6 * U;
    constexpr int SPW = 64 / U;              // sequences per wave
    __shared__ float Ul[U * U3];
    __shared__ float hshare[4 * 64];

    const int tid = threadIdx.x;
    const int dir = blockIdx.x / NB;         // 0 fwd, 1 bwd
    const int blk = blockIdx.x % NB;
    const float* Uw = dir ? Uwb : Uwf;
    const float* br = dir ? brb : brf;
    const int nthreads = blockDim.x;

    for (int i = tid; i < U * U3; i += nthreads) {
        int j = i / U3, rem = i % U3;
        int g = rem / U, kp = rem % U;
        Ul[(j * U + kp) * 3 + g] = Uw[i];
    }
    __syncthreads();

    const int lane = tid & 63, wave = tid >> 6;
    const int kp   = lane % U;
    const int half = lane / U;
    const int seqid = wave * SPW + half;
    const int SPB = (nthreads >> 6) * SPW;
    const long batch = (long)blk * SPB + seqid;

    const float brz = br[kp], brr = br[U + kp], brh = br[2 * U + kp];
    float h = 0.f;
    const float* xzb = xz + batch * (long)T_ * NC + dir * U3;

    for (int tt = 0; tt < T_; tt++) {
        int t = dir ? (T_ - 1 - tt) : tt;
        const float* xr = xzb + (long)t * NC;
        float xzz = xr[kp], xzr = xr[U + kp], xzh = xr[2 * U + kp];
        float accz = brz, accr = brr, acch = brh;

        if (U == 64) {
            #pragma unroll
            for (int j = 0; j < 64; j++) {
#if __has_builtin(__builtin_amdgcn_readlane)
                float hj = __builtin_bit_cast(float,
                    __builtin_amdgcn_readlane(__builtin_bit_cast(int, h), j));
#else
                float hj = __shfl(h, j, 64);
#endif
                const float* up = &Ul[(j * U + kp) * 3];
                accz = fmaf(hj, up[0], accz);
                accr = fmaf(hj, up[1], accr);
                acch = fmaf(hj, up[2], acch);
            }
        } else {
            hshare[seqid * U + kp] = h;      // wave-local exchange (lockstep)
            #pragma unroll
            for (int j = 0; j < U; j++) {
                float hj = hshare[seqid * U + j];
                const float* up = &Ul[(j * U + kp) * 3];
                accz = fmaf(hj, up[0], accz);
                accr = fmaf(hj, up[1], accr);
                acch = fmaf(hj, up[2], acch);
            }
        }

        float z = 1.f / (1.f + expf(-(xzz + accz)));
        float r = 1.f / (1.f + expf(-(xzr + accr)));
        float hh = fmaxf(xzh + r * acch, 0.f);
        h = fmaf(z, h - hh, hh);

        if (WRITE_ALL) {
            long row = batch * T_ + t;
            out[row * (2 * U) + dir * U + kp] = h;
        }
    }
    if (!WRITE_ALL)
        out[batch * (2 * U) + dir * U + kp] = h;
}

// ---------------------------------------------------------------------------
// dense + exp + per-(row, colblock) partial sums.
// Block: 256 threads, 64 rows x 256 cols tile. h3 tile transposed in LDS ->
// broadcast reads. Logits are tiny -> skip max subtraction (exact softmax).
// ---------------------------------------------------------------------------
__global__ void dense_exp_kernel(const float* __restrict__ h3, const float* __restrict__ Wd,
                                 const float* __restrict__ bd, float* __restrict__ out,
                                 float* __restrict__ partials)
{
    constexpr int RW = 64;
    __shared__ float ht[64 * RW];   // [k][r]
    __shared__ float red[4 * RW];
    const int tid = threadIdx.x;
    const int row0 = blockIdx.y * RW;
    const int col = blockIdx.x * 256 + tid;

    for (int i = tid; i < RW * 16; i += 256) {
        int r = i / 16, q = i % 16;
        float4 v = *(const float4*)(h3 + (long)(row0 + r) * 64 + q * 4);
        ht[(q * 4 + 0) * RW + r] = v.x;
        ht[(q * 4 + 1) * RW + r] = v.y;
        ht[(q * 4 + 2) * RW + r] = v.z;
        ht[(q * 4 + 3) * RW + r] = v.w;
    }
    __syncthreads();

    float acc[RW];
    #pragma unroll
    for (int r = 0; r < RW; r++) acc[r] = 0.f;
    const bool valid = col < VOCAB_;
    const float* wcol = Wd + col;

    for (int k = 0; k < 64; k++) {
        float w = valid ? wcol[(long)k * VOCAB_] : 0.f;
        const float4* h4 = (const float4*)&ht[k * RW];
        #pragma unroll
        for (int r4 = 0; r4 < RW / 4; r4++) {
            float4 hv = h4[r4];
            acc[r4 * 4 + 0] = fmaf(w, hv.x, acc[r4 * 4 + 0]);
            acc[r4 * 4 + 1] = fmaf(w, hv.y, acc[r4 * 4 + 1]);
            acc[r4 * 4 + 2] = fmaf(w, hv.z, acc[r4 * 4 + 2]);
            acc[r4 * 4 + 3] = fmaf(w, hv.w, acc[r4 * 4 + 3]);
        }
    }
    const float bdv = valid ? bd[col] : 0.f;
    const int lane = tid & 63, wv = tid >> 6;

    #pragma unroll
    for (int r = 0; r < RW; r++) {
        float e = valid ? expf(acc[r] + bdv) : 0.f;
        if (valid) out[(long)(row0 + r) * VOCAB_ + col] = e;
        for (int off = 32; off; off >>= 1) e += __shfl_down(e, off);
        if (lane == 0) red[wv * RW + r] = e;
    }
    __syncthreads();
    for (int r = tid; r < RW; r += 256) {
        float s = red[0 * RW + r] + red[1 * RW + r] + red[2 * RW + r] + red[3 * RW + r];
        partials[(long)blockIdx.x * B_ + row0 + r] = s;
    }
}

__global__ void rowsum_kernel(const float* __restrict__ partials,
                              float* __restrict__ rinv, int ncolblk)
{
    int row = blockIdx.x * blockDim.x + threadIdx.x;
    if (row >= B_) return;
    float s = 0.f;
    for (int p = 0; p < ncolblk; p++) s += partials[(long)p * B_ + row];
    rinv[row] = 1.f / s;
}

__global__ void scale_kernel(float* __restrict__ out, const float* __restrict__ rinv)
{
    const unsigned n4 = (unsigned)B_ * VOCAB_ / 4u;   // 6.4M float4
    const unsigned c4 = VOCAB_ / 4u;                  // 12500, row-aligned
    for (unsigned i = blockIdx.x * blockDim.x + threadIdx.x; i < n4;
         i += gridDim.x * blockDim.x) {
        unsigned row = i / c4;
        float s = rinv[row];
        float4 v = ((float4*)out)[i];
        v.x *= s; v.y *= s; v.z *= s; v.w *= s;
        ((float4*)out)[i] = v;
    }
}

// ---------------------------------------------------------------------------
extern "C" void kernel_launch(void* const* d_in, const int* in_sizes, int n_in,
                              void* d_out, int out_size, void* d_ws, size_t ws_size,
                              hipStream_t stream)
{
    const int*   x    = (const int*)  d_in[0];
    const float* emb  = (const float*)d_in[1];
    const float* W1f  = (const float*)d_in[2];
    const float* U1f  = (const float*)d_in[3];
    const float* bi1f = (const float*)d_in[4];
    const float* br1f = (const float*)d_in[5];
    const float* W1b  = (const float*)d_in[6];
    const float* U1b  = (const float*)d_in[7];
    const float* bi1b = (const float*)d_in[8];
    const float* br1b = (const float*)d_in[9];
    const float* W2f  = (const float*)d_in[10];
    const float* U2f  = (const float*)d_in[11];
    const float* bi2f = (const float*)d_in[12];
    const float* br2f = (const float*)d_in[13];
    const float* W2b  = (const float*)d_in[14];
    const float* U2b  = (const float*)d_in[15];
    const float* bi2b = (const float*)d_in[16];
    const float* br2b = (const float*)d_in[17];
    const float* W3f  = (const float*)d_in[18];
    const float* U3f  = (const float*)d_in[19];
    const float* bi3f = (const float*)d_in[20];
    const float* br3f = (const float*)d_in[21];
    const float* W3b  = (const float*)d_in[22];
    const float* U3b  = (const float*)d_in[23];
    const float* bi3b = (const float*)d_in[24];
    const float* br3b = (const float*)d_in[25];
    const float* Wd   = (const float*)d_in[26];
    const float* bd   = (const float*)d_in[27];

    const long NROWS = (long)B_ * T_;        // 65536
    const int  NCB   = (VOCAB_ + 255) / 256; // 196 col blocks

    // xz buffers live in d_out (largest need: 65536*384*4 = 100.7MB <= 102.4MB)
    float* xz = (float*)d_out;

    // workspace layout
    char* w = (char*)d_ws;
    float* h1 = (float*)w;            w += NROWS * 128 * sizeof(float); // 33.6MB
    float* h2 = (float*)w;            w += NROWS * 64  * sizeof(float); // 16.8MB
    float* h3 = (float*)w;            w += (long)B_ * 64 * sizeof(float);
    float* partials = (float*)w;      w += (long)NCB * B_ * sizeof(float);
    float* rinv = (float*)w;          w += B_ * sizeof(float);

    // layer 1: embed+proj -> xz (d_out), recurrence -> h1
    proj_kernel<128, 192, true><<<NROWS / 8, 128, 0, stream>>>(
        nullptr, x, emb, W1f, W1b, bi1f, bi1b, xz);
    gru_rec_kernel<64, true><<<256, 256, 0, stream>>>(
        xz, U1f, U1b, br1f, br1b, h1, 128);

    // layer 2
    proj_kernel<128, 96, false><<<NROWS / 8, 64, 0, stream>>>(
        h1, nullptr, nullptr, W2f, W2b, bi2f, bi2b, xz);
    gru_rec_kernel<32, true><<<256, 128, 0, stream>>>(
        xz, U2f, U2b, br2f, br2b, h2, 128);

    // layer 3 (final states only)
    proj_kernel<64, 96, false><<<NROWS / 8, 64, 0, stream>>>(
        h2, nullptr, nullptr, W3f, W3b, bi3f, bi3b, xz);
    gru_rec_kernel<32, false><<<256, 128, 0, stream>>>(
        xz, U3f, U3b, br3f, br3b, h3, 128);

    // dense -> exp -> d_out, partial row sums -> reduce -> scale
    dense_exp_kernel<<<dim3(NCB, B_ / 64), 256, 0, stream>>>(
        h3, Wd, bd, (float*)d_out, partials);
    rowsum_kernel<<<(B_ + 255) / 256, 256, 0, stream>>>(partials, rinv, NCB);
    scale_kernel<<<2048, 256, 0, stream>>>((float*)d_out, rinv);
}

// Round 6
// 838.992 us; speedup vs baseline: 2.0221x; 2.0221x over previous
//
#include <hip/hip_runtime.h>
#include <math.h>

#define B_ 512
#define T_ 128
#define VOCAB_ 50000

// ---------------------------------------------------------------------------
// proj kernel: out[row][0:2*U3] = concat(in_row @ Wf + bif, in_row @ Wb + bib)
// rows are (b,t) pairs, linear. If GATHER, in_row = emb[idx[row]].
// Block: TPB = 2*U3/3 threads; thread owns 3 cols {tid, tid+TPB, tid+2*TPB}.
// ROWS=8 rows per block; input tile staged transposed in LDS -> all inner
// reads are same-address broadcasts (conflict-free).
// ---------------------------------------------------------------------------
template<int K, int U3, bool GATHER>
__global__ void proj_kernel(const float* __restrict__ in,
                            const int* __restrict__ idx,
                            const float* __restrict__ emb,
                            const float* __restrict__ Wf, const float* __restrict__ Wb,
                            const float* __restrict__ bif, const float* __restrict__ bib,
                            float* __restrict__ out)
{
    constexpr int TPB  = 2 * U3 / 3;   // 128 (U3=192) or 64 (U3=96)
    constexpr int ROWS = 8;
    constexpr int NC   = 2 * U3;
    __shared__ float et[K * ROWS];     // [k][r]
    const int tid = threadIdx.x;
    const long row0 = (long)blockIdx.x * ROWS;

    constexpr int F4 = K / 4;          // float4 per row
    for (int i = tid; i < ROWS * F4; i += TPB) {
        int r = i / F4, q = i % F4;
        const float* src;
        if (GATHER) src = emb + (long)idx[row0 + r] * K + q * 4;
        else        src = in  + (row0 + r) * (long)K + q * 4;
        float4 v = *(const float4*)src;
        et[(q * 4 + 0) * ROWS + r] = v.x;
        et[(q * 4 + 1) * ROWS + r] = v.y;
        et[(q * 4 + 2) * ROWS + r] = v.z;
        et[(q * 4 + 3) * ROWS + r] = v.w;
    }
    __syncthreads();

    const float* wp[3];
    float acc[3][ROWS];
    #pragma unroll
    for (int g = 0; g < 3; g++) {
        int col = tid + g * TPB;
        const float* W  = (col < U3) ? Wf  : Wb;
        const float* bi = (col < U3) ? bif : bib;
        int cc = (col < U3) ? col : col - U3;
        wp[g] = W + cc;
        float b = bi[cc];
        #pragma unroll
        for (int r = 0; r < ROWS; r++) acc[g][r] = b;
    }

    for (int k = 0; k < K; k++) {
        float w0 = wp[0][(long)k * U3];
        float w1 = wp[1][(long)k * U3];
        float w2 = wp[2][(long)k * U3];
        const float4* e4 = (const float4*)&et[k * ROWS];
        float4 ea = e4[0], eb = e4[1];
        float ev[8] = {ea.x, ea.y, ea.z, ea.w, eb.x, eb.y, eb.z, eb.w};
        #pragma unroll
        for (int r = 0; r < ROWS; r++) {
            acc[0][r] = fmaf(ev[r], w0, acc[0][r]);
            acc[1][r] = fmaf(ev[r], w1, acc[1][r]);
            acc[2][r] = fmaf(ev[r], w2, acc[2][r]);
        }
    }

    #pragma unroll
    for (int g = 0; g < 3; g++) {
        int col = tid + g * TPB;
        for (int r = 0; r < ROWS; r++)
            out[(row0 + r) * NC + col] = acc[g][r];
    }
}

// ---------------------------------------------------------------------------
// GRU recurrence, weight-stationary. 1 wave per block.
// U==64: 1 sequence/wave, lane owns cols {c, 64+c, 128+c}; weights in 192
//        VGPRs; h broadcast via v_readlane (no memory in inner loop).
// U==32: 2 sequences/wave (half = lane>>5); weights in 96 VGPRs; h exchanged
//        through a 64-float LDS buffer, bulk-read as 8x broadcast b128 into
//        regs (single waitcnt), then 96 reg-only FMAs.
// xz rows are prefetched 2 timesteps ahead (hand-unrolled x2 for static regs).
// ---------------------------------------------------------------------------
template<int U, bool WRITE_ALL>
__global__ __launch_bounds__(64, 1)
void gru_rec_kernel(const float* __restrict__ xz,   // [B*T][6U]
                    const float* __restrict__ Uwf, const float* __restrict__ Uwb,
                    const float* __restrict__ brf, const float* __restrict__ brb,
                    float* __restrict__ out, int NB)
{
    constexpr int U3 = 3 * U;
    constexpr int NC = 6 * U;
    const int lane = threadIdx.x;
    const int dir = blockIdx.x / NB;         // 0 fwd, 1 bwd
    const int blk = blockIdx.x % NB;
    const float* Uw = dir ? Uwb : Uwf;
    const float* br = dir ? brb : brf;

    int kp, half;
    long batch;
    if constexpr (U == 64) { kp = lane; half = 0; batch = blk; }
    else { kp = lane & 31; half = lane >> 5; batch = (long)blk * 2 + half; }

    // ---- stage recurrent weights into registers (coalesced) ----
    float wz[U], wr[U], wh[U];
    #pragma unroll
    for (int j = 0; j < U; j++) {
        wz[j] = Uw[j * U3 + kp];
        wr[j] = Uw[j * U3 + U + kp];
        wh[j] = Uw[j * U3 + 2 * U + kp];
    }
    const float brz = br[kp], brr = br[U + kp], brh = br[2 * U + kp];

    __shared__ float hsh[64];                // used only for U==32
    float h = 0.f;
    const float* xzb = xz + batch * (long)T_ * NC + dir * U3;

    auto rowp = [&](int tt) -> const float* {
        int t = dir ? (T_ - 1 - tt) : tt;
        return xzb + (long)t * NC;
    };

    // depth-2 prefetch buffers (statically indexed via x2 unroll)
    const float* r0 = rowp(0);
    const float* r1 = rowp(1);
    float p0z = r0[kp], p0r = r0[U + kp], p0h = r0[2 * U + kp];
    float p1z = r1[kp], p1r = r1[U + kp], p1h = r1[2 * U + kp];

    auto step = [&](int tt, float& pz, float& pr, float& ph) {
        float xzz = pz, xzr = pr, xzh = ph;
        if (tt + 2 < T_) {                   // prefetch t+2 into freed slot
            const float* q = rowp(tt + 2);
            pz = q[kp]; pr = q[U + kp]; ph = q[2 * U + kp];
        }
        float accz = brz, accr = brr, acch = brh;

        if constexpr (U == 64) {
            #pragma unroll
            for (int j = 0; j < 64; j++) {
                float hj = __builtin_bit_cast(float,
                    __builtin_amdgcn_readlane(__builtin_bit_cast(int, h), j));
                accz = fmaf(hj, wz[j], accz);
                accr = fmaf(hj, wr[j], accr);
                acch = fmaf(hj, wh[j], acch);
            }
        } else {
            hsh[lane] = h;                   // wave-local, lockstep: no barrier
            float ha[32];
            const float4* hv = (const float4*)&hsh[half * 32];
            #pragma unroll
            for (int q4 = 0; q4 < 8; q4++) { // 2-addr broadcast reads: free
                float4 v = hv[q4];
                ha[q4 * 4 + 0] = v.x; ha[q4 * 4 + 1] = v.y;
                ha[q4 * 4 + 2] = v.z; ha[q4 * 4 + 3] = v.w;
            }
            #pragma unroll
            for (int j = 0; j < 32; j++) {
                accz = fmaf(ha[j], wz[j], accz);
                accr = fmaf(ha[j], wr[j], accr);
                acch = fmaf(ha[j], wh[j], acch);
            }
        }

        float z = 1.f / (1.f + expf(-(xzz + accz)));
        float r = 1.f / (1.f + expf(-(xzr + accr)));
        float hh = fmaxf(xzh + r * acch, 0.f);
        h = fmaf(z, h - hh, hh);

        if (WRITE_ALL) {
            int t = dir ? (T_ - 1 - tt) : tt;
            long row = batch * T_ + t;
            out[row * (2 * U) + dir * U + kp] = h;
        }
    };

    for (int tt = 0; tt < T_; tt += 2) {
        step(tt,     p0z, p0r, p0h);
        step(tt + 1, p1z, p1r, p1h);
    }
    if (!WRITE_ALL)
        out[batch * (2 * U) + dir * U + kp] = h;
}

// ---------------------------------------------------------------------------
// dense + exp + per-(row, colblock) partial sums.
// Block: 256 threads, 64 rows x 256 cols tile. h3 tile transposed in LDS ->
// broadcast reads. Logits are tiny -> skip max subtraction (exact softmax).
// ---------------------------------------------------------------------------
__global__ void dense_exp_kernel(const float* __restrict__ h3, const float* __restrict__ Wd,
                                 const float* __restrict__ bd, float* __restrict__ out,
                                 float* __restrict__ partials)
{
    constexpr int RW = 64;
    __shared__ float ht[64 * RW];   // [k][r]
    __shared__ float red[4 * RW];
    const int tid = threadIdx.x;
    const int row0 = blockIdx.y * RW;
    const int col = blockIdx.x * 256 + tid;

    for (int i = tid; i < RW * 16; i += 256) {
        int r = i / 16, q = i % 16;
        float4 v = *(const float4*)(h3 + (long)(row0 + r) * 64 + q * 4);
        ht[(q * 4 + 0) * RW + r] = v.x;
        ht[(q * 4 + 1) * RW + r] = v.y;
        ht[(q * 4 + 2) * RW + r] = v.z;
        ht[(q * 4 + 3) * RW + r] = v.w;
    }
    __syncthreads();

    float acc[RW];
    #pragma unroll
    for (int r = 0; r < RW; r++) acc[r] = 0.f;
    const bool valid = col < VOCAB_;
    const float* wcol = Wd + col;

    for (int k = 0; k < 64; k++) {
        float w = valid ? wcol[(long)k * VOCAB_] : 0.f;
        const float4* h4 = (const float4*)&ht[k * RW];
        #pragma unroll
        for (int r4 = 0; r4 < RW / 4; r4++) {
            float4 hv = h4[r4];
            acc[r4 * 4 + 0] = fmaf(w, hv.x, acc[r4 * 4 + 0]);
            acc[r4 * 4 + 1] = fmaf(w, hv.y, acc[r4 * 4 + 1]);
            acc[r4 * 4 + 2] = fmaf(w, hv.z, acc[r4 * 4 + 2]);
            acc[r4 * 4 + 3] = fmaf(w, hv.w, acc[r4 * 4 + 3]);
        }
    }
    const float bdv = valid ? bd[col] : 0.f;
    const int lane = tid & 63, wv = tid >> 6;

    #pragma unroll
    for (int r = 0; r < RW; r++) {
        float e = valid ? expf(acc[r] + bdv) : 0.f;
        if (valid) out[(long)(row0 + r) * VOCAB_ + col] = e;
        for (int off = 32; off; off >>= 1) e += __shfl_down(e, off);
        if (lane == 0) red[wv * RW + r] = e;
    }
    __syncthreads();
    for (int r = tid; r < RW; r += 256) {
        float s = red[0 * RW + r] + red[1 * RW + r] + red[2 * RW + r] + red[3 * RW + r];
        partials[(long)blockIdx.x * B_ + row0 + r] = s;
    }
}

__global__ void rowsum_kernel(const float* __restrict__ partials,
                              float* __restrict__ rinv, int ncolblk)
{
    int row = blockIdx.x * blockDim.x + threadIdx.x;
    if (row >= B_) return;
    float s = 0.f;
    for (int p = 0; p < ncolblk; p++) s += partials[(long)p * B_ + row];
    rinv[row] = 1.f / s;
}

__global__ void scale_kernel(float* __restrict__ out, const float* __restrict__ rinv)
{
    const unsigned n4 = (unsigned)B_ * VOCAB_ / 4u;   // 6.4M float4
    const unsigned c4 = VOCAB_ / 4u;                  // 12500, row-aligned
    for (unsigned i = blockIdx.x * blockDim.x + threadIdx.x; i < n4;
         i += gridDim.x * blockDim.x) {
        unsigned row = i / c4;
        float s = rinv[row];
        float4 v = ((float4*)out)[i];
        v.x *= s; v.y *= s; v.z *= s; v.w *= s;
        ((float4*)out)[i] = v;
    }
}

// ---------------------------------------------------------------------------
extern "C" void kernel_launch(void* const* d_in, const int* in_sizes, int n_in,
                              void* d_out, int out_size, void* d_ws, size_t ws_size,
                              hipStream_t stream)
{
    const int*   x    = (const int*)  d_in[0];
    const float* emb  = (const float*)d_in[1];
    const float* W1f  = (const float*)d_in[2];
    const float* U1f  = (const float*)d_in[3];
    const float* bi1f = (const float*)d_in[4];
    const float* br1f = (const float*)d_in[5];
    const float* W1b  = (const float*)d_in[6];
    const float* U1b  = (const float*)d_in[7];
    const float* bi1b = (const float*)d_in[8];
    const float* br1b = (const float*)d_in[9];
    const float* W2f  = (const float*)d_in[10];
    const float* U2f  = (const float*)d_in[11];
    const float* bi2f = (const float*)d_in[12];
    const float* br2f = (const float*)d_in[13];
    const float* W2b  = (const float*)d_in[14];
    const float* U2b  = (const float*)d_in[15];
    const float* bi2b = (const float*)d_in[16];
    const float* br2b = (const float*)d_in[17];
    const float* W3f  = (const float*)d_in[18];
    const float* U3f  = (const float*)d_in[19];
    const float* bi3f = (const float*)d_in[20];
    const float* br3f = (const float*)d_in[21];
    const float* W3b  = (const float*)d_in[22];
    const float* U3b  = (const float*)d_in[23];
    const float* bi3b = (const float*)d_in[24];
    const float* br3b = (const float*)d_in[25];
    const float* Wd   = (const float*)d_in[26];
    const float* bd   = (const float*)d_in[27];

    const long NROWS = (long)B_ * T_;        // 65536
    const int  NCB   = (VOCAB_ + 255) / 256; // 196 col blocks

    // xz buffers live in d_out (largest need: 65536*384*4 = 100.7MB <= 102.4MB)
    float* xz = (float*)d_out;

    // workspace layout
    char* w = (char*)d_ws;
    float* h1 = (float*)w;            w += NROWS * 128 * sizeof(float); // 33.6MB
    float* h2 = (float*)w;            w += NROWS * 64  * sizeof(float); // 16.8MB
    float* h3 = (float*)w;            w += (long)B_ * 64 * sizeof(float);
    float* partials = (float*)w;      w += (long)NCB * B_ * sizeof(float);
    float* rinv = (float*)w;          w += B_ * sizeof(float);

    // layer 1: embed+proj -> xz (d_out), recurrence -> h1
    proj_kernel<128, 192, true><<<NROWS / 8, 128, 0, stream>>>(
        nullptr, x, emb, W1f, W1b, bi1f, bi1b, xz);
    gru_rec_kernel<64, true><<<1024, 64, 0, stream>>>(
        xz, U1f, U1b, br1f, br1b, h1, 512);

    // layer 2
    proj_kernel<128, 96, false><<<NROWS / 8, 64, 0, stream>>>(
        h1, nullptr, nullptr, W2f, W2b, bi2f, bi2b, xz);
    gru_rec_kernel<32, true><<<512, 64, 0, stream>>>(
        xz, U2f, U2b, br2f, br2b, h2, 256);

    // layer 3 (final states only)
    proj_kernel<64, 96, false><<<NROWS / 8, 64, 0, stream>>>(
        h2, nullptr, nullptr, W3f, W3b, bi3f, bi3b, xz);
    gru_rec_kernel<32, false><<<512, 64, 0, stream>>>(
        xz, U3f, U3b, br3f, br3b, h3, 256);

    // dense -> exp -> d_out, partial row sums -> reduce -> scale
    dense_exp_kernel<<<dim3(NCB, B_ / 64), 256, 0, stream>>>(
        h3, Wd, bd, (float*)d_out, partials);
    rowsum_kernel<<<(B_ + 255) / 256, 256, 0, stream>>>(partials, rinv, NCB);
    scale_kernel<<<2048, 256, 0, stream>>>((float*)d_out, rinv);
}

// Round 7
// 824.864 us; speedup vs baseline: 2.0567x; 1.0171x over previous
//
#include <hip/hip_runtime.h>
#include <math.h>

#define B_ 512
#define T_ 128
#define VOCAB_ 50000

// ---- guaranteed-static unroll helper (rule #20: no runtime-indexed arrays) ----
template<int I> struct IC { static constexpr int v = I; };
template<int I, int N, typename F>
__device__ __forceinline__ void sfor(F f) {
    if constexpr (I < N) { f(IC<I>{}); sfor<I + 1, N>(f); }
}

// ---------------------------------------------------------------------------
// proj kernel: out[row][0:2*U3] = concat(in_row @ Wf + bif, in_row @ Wb + bib)
// rows are (b,t) pairs, linear. If GATHER, in_row = emb[idx[row]].
// ---------------------------------------------------------------------------
template<int K, int U3, bool GATHER>
__global__ void proj_kernel(const float* __restrict__ in,
                            const int* __restrict__ idx,
                            const float* __restrict__ emb,
                            const float* __restrict__ Wf, const float* __restrict__ Wb,
                            const float* __restrict__ bif, const float* __restrict__ bib,
                            float* __restrict__ out)
{
    constexpr int TPB  = 2 * U3 / 3;   // 128 (U3=192) or 64 (U3=96)
    constexpr int ROWS = 8;
    constexpr int NC   = 2 * U3;
    __shared__ float et[K * ROWS];     // [k][r]
    const int tid = threadIdx.x;
    const long row0 = (long)blockIdx.x * ROWS;

    constexpr int F4 = K / 4;          // float4 per row
    for (int i = tid; i < ROWS * F4; i += TPB) {
        int r = i / F4, q = i % F4;
        const float* src;
        if (GATHER) src = emb + (long)idx[row0 + r] * K + q * 4;
        else        src = in  + (row0 + r) * (long)K + q * 4;
        float4 v = *(const float4*)src;
        et[(q * 4 + 0) * ROWS + r] = v.x;
        et[(q * 4 + 1) * ROWS + r] = v.y;
        et[(q * 4 + 2) * ROWS + r] = v.z;
        et[(q * 4 + 3) * ROWS + r] = v.w;
    }
    __syncthreads();

    const float* wp[3];
    float acc[3][ROWS];
    #pragma unroll
    for (int g = 0; g < 3; g++) {
        int col = tid + g * TPB;
        const float* W  = (col < U3) ? Wf  : Wb;
        const float* bi = (col < U3) ? bif : bib;
        int cc = (col < U3) ? col : col - U3;
        wp[g] = W + cc;
        float b = bi[cc];
        #pragma unroll
        for (int r = 0; r < ROWS; r++) acc[g][r] = b;
    }

    for (int k = 0; k < K; k++) {
        float w0 = wp[0][(long)k * U3];
        float w1 = wp[1][(long)k * U3];
        float w2 = wp[2][(long)k * U3];
        const float4* e4 = (const float4*)&et[k * ROWS];
        float4 ea = e4[0], eb = e4[1];
        float ev[8] = {ea.x, ea.y, ea.z, ea.w, eb.x, eb.y, eb.z, eb.w};
        #pragma unroll
        for (int r = 0; r < ROWS; r++) {
            acc[0][r] = fmaf(ev[r], w0, acc[0][r]);
            acc[1][r] = fmaf(ev[r], w1, acc[1][r]);
            acc[2][r] = fmaf(ev[r], w2, acc[2][r]);
        }
    }

    #pragma unroll
    for (int g = 0; g < 3; g++) {
        int col = tid + g * TPB;
        for (int r = 0; r < ROWS; r++)
            out[(row0 + r) * NC + col] = acc[g][r];
    }
}

// ---------------------------------------------------------------------------
// GRU recurrence, weight-stationary, STATIC-unrolled (sfor) so the per-lane
// weight arrays are provably register-resident (VGPR ~220 for U=64).
// U==64: 1 seq/wave; lane c owns cols {c,64+c,128+c}; h broadcast v_readlane.
// U==32: 2 seqs/wave; h exchanged via 64-float LDS buffer, bulk b128 reads.
// 6 independent FMA accumulation chains (even/odd split per gate).
// xz prefetched 2 steps ahead in statically-indexed regs (x2 unroll).
// ---------------------------------------------------------------------------
template<int U, bool WRITE_ALL>
__global__ __launch_bounds__(64, 1)
void gru_rec_kernel(const float* __restrict__ xz,   // [B*T][6U]
                    const float* __restrict__ Uwf, const float* __restrict__ Uwb,
                    const float* __restrict__ brf, const float* __restrict__ brb,
                    float* __restrict__ out, int NB)
{
    constexpr int U3 = 3 * U;
    constexpr int NC = 6 * U;
    const int lane = threadIdx.x;
    const int dir = blockIdx.x / NB;         // 0 fwd, 1 bwd
    const int blk = blockIdx.x % NB;
    const float* Uw = dir ? Uwb : Uwf;
    const float* br = dir ? brb : brf;

    int kp, half;
    long batch;
    if constexpr (U == 64) { kp = lane; half = 0; batch = blk; }
    else { kp = lane & 31; half = lane >> 5; batch = (long)blk * 2 + half; }

    // ---- stage recurrent weights into registers (static indices) ----
    float wz[U], wr[U], wh[U];
    sfor<0, U>([&](auto ic) {
        constexpr int j = decltype(ic)::v;
        wz[j] = Uw[j * U3 + kp];
        wr[j] = Uw[j * U3 + U + kp];
        wh[j] = Uw[j * U3 + 2 * U + kp];
    });
    const float brz = br[kp], brr = br[U + kp], brh = br[2 * U + kp];

    __shared__ float hsh[64];                // used only for U==32
    float h = 0.f;
    const float* xzb = xz + batch * (long)T_ * NC + dir * U3;

    auto rowp = [&](int tt) -> const float* {
        int t = dir ? (T_ - 1 - tt) : tt;
        return xzb + (long)t * NC;
    };

    // depth-2 prefetch buffers (statically indexed via x2 unroll)
    const float* r0 = rowp(0);
    const float* r1 = rowp(1);
    float p0z = r0[kp], p0r = r0[U + kp], p0h = r0[2 * U + kp];
    float p1z = r1[kp], p1r = r1[U + kp], p1h = r1[2 * U + kp];

    auto step = [&](int tt, float& pz, float& pr, float& ph) {
        float xzz = pz, xzr = pr, xzh = ph;
        if (tt + 2 < T_) {                   // prefetch t+2 into freed slot
            const float* q = rowp(tt + 2);
            pz = q[kp]; pr = q[U + kp]; ph = q[2 * U + kp];
        }
        // 6 independent chains (even/odd per gate)
        float az0 = 0.f, az1 = 0.f, ar0 = 0.f, ar1 = 0.f, ah0 = 0.f, ah1 = 0.f;

        if constexpr (U == 64) {
            sfor<0, 64>([&](auto ic) {
                constexpr int j = decltype(ic)::v;
                float hj = __builtin_bit_cast(float,
                    __builtin_amdgcn_readlane(__builtin_bit_cast(int, h), j));
                if constexpr ((j & 1) == 0) {
                    az0 = fmaf(hj, wz[j], az0);
                    ar0 = fmaf(hj, wr[j], ar0);
                    ah0 = fmaf(hj, wh[j], ah0);
                } else {
                    az1 = fmaf(hj, wz[j], az1);
                    ar1 = fmaf(hj, wr[j], ar1);
                    ah1 = fmaf(hj, wh[j], ah1);
                }
            });
        } else {
            hsh[lane] = h;                   // wave-local, lockstep: no barrier
            float ha[32];
            const float4* hv = (const float4*)&hsh[half * 32];
            sfor<0, 8>([&](auto icq) {       // 2-addr broadcast reads: free
                constexpr int q4 = decltype(icq)::v;
                float4 v = hv[q4];
                ha[q4 * 4 + 0] = v.x; ha[q4 * 4 + 1] = v.y;
                ha[q4 * 4 + 2] = v.z; ha[q4 * 4 + 3] = v.w;
            });
            sfor<0, 32>([&](auto ic) {
                constexpr int j = decltype(ic)::v;
                if constexpr ((j & 1) == 0) {
                    az0 = fmaf(ha[j], wz[j], az0);
                    ar0 = fmaf(ha[j], wr[j], ar0);
                    ah0 = fmaf(ha[j], wh[j], ah0);
                } else {
                    az1 = fmaf(ha[j], wz[j], az1);
                    ar1 = fmaf(ha[j], wr[j], ar1);
                    ah1 = fmaf(ha[j], wh[j], ah1);
                }
            });
        }
        float accz = brz + az0 + az1;
        float accr = brr + ar0 + ar1;
        float acch = brh + ah0 + ah1;

        float z = 1.f / (1.f + expf(-(xzz + accz)));
        float r = 1.f / (1.f + expf(-(xzr + accr)));
        float hh = fmaxf(xzh + r * acch, 0.f);
        h = fmaf(z, h - hh, hh);

        if (WRITE_ALL) {
            int t = dir ? (T_ - 1 - tt) : tt;
            long row = batch * T_ + t;
            out[row * (2 * U) + dir * U + kp] = h;
        }
    };

    for (int tt = 0; tt < T_; tt += 2) {
        step(tt,     p0z, p0r, p0h);
        step(tt + 1, p1z, p1r, p1h);
    }
    if (!WRITE_ALL)
        out[batch * (2 * U) + dir * U + kp] = h;
}

// ---------------------------------------------------------------------------
// dense + exp + per-(row, colblock) partial sums.
// ---------------------------------------------------------------------------
__global__ void dense_exp_kernel(const float* __restrict__ h3, const float* __restrict__ Wd,
                                 const float* __restrict__ bd, float* __restrict__ out,
                                 float* __restrict__ partials)
{
    constexpr int RW = 64;
    __shared__ float ht[64 * RW];   // [k][r]
    __shared__ float red[4 * RW];
    const int tid = threadIdx.x;
    const int row0 = blockIdx.y * RW;
    const int col = blockIdx.x * 256 + tid;

    for (int i = tid; i < RW * 16; i += 256) {
        int r = i / 16, q = i % 16;
        float4 v = *(const float4*)(h3 + (long)(row0 + r) * 64 + q * 4);
        ht[(q * 4 + 0) * RW + r] = v.x;
        ht[(q * 4 + 1) * RW + r] = v.y;
        ht[(q * 4 + 2) * RW + r] = v.z;
        ht[(q * 4 + 3) * RW + r] = v.w;
    }
    __syncthreads();

    float acc[RW];
    #pragma unroll
    for (int r = 0; r < RW; r++) acc[r] = 0.f;
    const bool valid = col < VOCAB_;
    const float* wcol = Wd + col;

    for (int k = 0; k < 64; k++) {
        float w = valid ? wcol[(long)k * VOCAB_] : 0.f;
        const float4* h4 = (const float4*)&ht[k * RW];
        #pragma unroll
        for (int r4 = 0; r4 < RW / 4; r4++) {
            float4 hv = h4[r4];
            acc[r4 * 4 + 0] = fmaf(w, hv.x, acc[r4 * 4 + 0]);
            acc[r4 * 4 + 1] = fmaf(w, hv.y, acc[r4 * 4 + 1]);
            acc[r4 * 4 + 2] = fmaf(w, hv.z, acc[r4 * 4 + 2]);
            acc[r4 * 4 + 3] = fmaf(w, hv.w, acc[r4 * 4 + 3]);
        }
    }
    const float bdv = valid ? bd[col] : 0.f;
    const int lane = tid & 63, wv = tid >> 6;

    #pragma unroll
    for (int r = 0; r < RW; r++) {
        float e = valid ? expf(acc[r] + bdv) : 0.f;
        if (valid) out[(long)(row0 + r) * VOCAB_ + col] = e;
        for (int off = 32; off; off >>= 1) e += __shfl_down(e, off);
        if (lane == 0) red[wv * RW + r] = e;
    }
    __syncthreads();
    for (int r = tid; r < RW; r += 256) {
        float s = red[0 * RW + r] + red[1 * RW + r] + red[2 * RW + r] + red[3 * RW + r];
        partials[(long)blockIdx.x * B_ + row0 + r] = s;
    }
}

__global__ void rowsum_kernel(const float* __restrict__ partials,
                              float* __restrict__ rinv, int ncolblk)
{
    int row = blockIdx.x * blockDim.x + threadIdx.x;
    if (row >= B_) return;
    float s = 0.f;
    for (int p = 0; p < ncolblk; p++) s += partials[(long)p * B_ + row];
    rinv[row] = 1.f / s;
}

__global__ void scale_kernel(float* __restrict__ out, const float* __restrict__ rinv)
{
    const unsigned n4 = (unsigned)B_ * VOCAB_ / 4u;   // 6.4M float4
    const unsigned c4 = VOCAB_ / 4u;                  // 12500, row-aligned
    for (unsigned i = blockIdx.x * blockDim.x + threadIdx.x; i < n4;
         i += gridDim.x * blockDim.x) {
        unsigned row = i / c4;
        float s = rinv[row];
        float4 v = ((float4*)out)[i];
        v.x *= s; v.y *= s; v.z *= s; v.w *= s;
        ((float4*)out)[i] = v;
    }
}

// ---------------------------------------------------------------------------
extern "C" void kernel_launch(void* const* d_in, const int* in_sizes, int n_in,
                              void* d_out, int out_size, void* d_ws, size_t ws_size,
                              hipStream_t stream)
{
    const int*   x    = (const int*)  d_in[0];
    const float* emb  = (const float*)d_in[1];
    const float* W1f  = (const float*)d_in[2];
    const float* U1f  = (const float*)d_in[3];
    const float* bi1f = (const float*)d_in[4];
    const float* br1f = (const float*)d_in[5];
    const float* W1b  = (const float*)d_in[6];
    const float* U1b  = (const float*)d_in[7];
    const float* bi1b = (const float*)d_in[8];
    const float* br1b = (const float*)d_in[9];
    const float* W2f  = (const float*)d_in[10];
    const float* U2f  = (const float*)d_in[11];
    const float* bi2f = (const float*)d_in[12];
    const float* br2f = (const float*)d_in[13];
    const float* W2b  = (const float*)d_in[14];
    const float* U2b  = (const float*)d_in[15];
    const float* bi2b = (const float*)d_in[16];
    const float* br2b = (const float*)d_in[17];
    const float* W3f  = (const float*)d_in[18];
    const float* U3f  = (const float*)d_in[19];
    const float* bi3f = (const float*)d_in[20];
    const float* br3f = (const float*)d_in[21];
    const float* W3b  = (const float*)d_in[22];
    const float* U3b  = (const float*)d_in[23];
    const float* bi3b = (const float*)d_in[24];
    const float* br3b = (const float*)d_in[25];
    const float* Wd   = (const float*)d_in[26];
    const float* bd   = (const float*)d_in[27];

    const long NROWS = (long)B_ * T_;        // 65536
    const int  NCB   = (VOCAB_ + 255) / 256; // 196 col blocks

    // xz buffers live in d_out (largest need: 65536*384*4 = 100.7MB <= 102.4MB)
    float* xz = (float*)d_out;

    // workspace layout
    char* w = (char*)d_ws;
    float* h1 = (float*)w;            w += NROWS * 128 * sizeof(float); // 33.6MB
    float* h2 = (float*)w;            w += NROWS * 64  * sizeof(float); // 16.8MB
    float* h3 = (float*)w;            w += (long)B_ * 64 * sizeof(float);
    float* partials = (float*)w;      w += (long)NCB * B_ * sizeof(float);
    float* rinv = (float*)w;          w += B_ * sizeof(float);

    // layer 1: embed+proj -> xz (d_out), recurrence -> h1
    proj_kernel<128, 192, true><<<NROWS / 8, 128, 0, stream>>>(
        nullptr, x, emb, W1f, W1b, bi1f, bi1b, xz);
    gru_rec_kernel<64, true><<<1024, 64, 0, stream>>>(
        xz, U1f, U1b, br1f, br1b, h1, 512);

    // layer 2
    proj_kernel<128, 96, false><<<NROWS / 8, 64, 0, stream>>>(
        h1, nullptr, nullptr, W2f, W2b, bi2f, bi2b, xz);
    gru_rec_kernel<32, true><<<512, 64, 0, stream>>>(
        xz, U2f, U2b, br2f, br2b, h2, 256);

    // layer 3 (final states only)
    proj_kernel<64, 96, false><<<NROWS / 8, 64, 0, stream>>>(
        h2, nullptr, nullptr, W3f, W3b, bi3f, bi3b, xz);
    gru_rec_kernel<32, false><<<512, 64, 0, stream>>>(
        xz, U3f, U3b, br3f, br3b, h3, 256);

    // dense -> exp -> d_out, partial row sums -> reduce -> scale
    dense_exp_kernel<<<dim3(NCB, B_ / 64), 256, 0, stream>>>(
        h3, Wd, bd, (float*)d_out, partials);
    rowsum_kernel<<<(B_ + 255) / 256, 256, 0, stream>>>(partials, rinv, NCB);
    scale_kernel<<<2048, 256, 0, stream>>>((float*)d_out, rinv);
}